// Round 9
// baseline (581.277 us; speedup 1.0000x reference)
//
#include <hip/hip_runtime.h>
#include <math.h>

#define NN 1024
#define NE 32768
#define NEE 262144
#define CS 384
#define CZ 128
#define CG 16
#define NH 4
#define NR 64

typedef __attribute__((ext_vector_type(8))) short short8v;
typedef __attribute__((ext_vector_type(4))) float f32x4;
typedef unsigned short ushort_t;

__device__ __forceinline__ float sigmoidf_(float x) { return 1.0f / (1.0f + __expf(-x)); }

__device__ __forceinline__ ushort_t f2bf(float x) {
    union { float f; unsigned u; } v; v.f = x;
    unsigned r = v.u + 0x7fff + ((v.u >> 16) & 1);
    return (ushort_t)(r >> 16);
}
__device__ __forceinline__ float bf2f(ushort_t x) {
    union { unsigned u; float f; } v; v.u = ((unsigned)x) << 16;
    return v.f;
}

// ---------------- node projections: nl16 (bf16) [N,16], nr (f32) [N,16] ----------------
__global__ void node_proj_kernel(const float* __restrict__ nf,
                                 const float* __restrict__ Wl, const float* __restrict__ bl,
                                 const float* __restrict__ Wr, const float* __restrict__ br,
                                 ushort_t* __restrict__ nl16, float* __restrict__ nr) {
    int wave = threadIdx.x >> 6, lane = threadIdx.x & 63;
    int n = blockIdx.x * 4 + wave;
    if (lane >= 32) return;
    bool isl = lane < 16;
    int o = isl ? lane : lane - 16;
    const float* W = isl ? Wl : Wr;
    float acc = isl ? bl[o] : br[o];
    const float* x = nf + n * CS;
    for (int k = 0; k < CS; ++k) acc += x[k] * W[k * 16 + o];
    if (isl) nl16[n * 16 + o] = f2bf(acc);
    else     nr[n * 16 + o] = acc;
}

// ---------------- Tbf[n][c][i] (bf16) = sum_j nr[n,j]*W_bg[(16i+j),c] ----------------
__global__ void build_Tt_kernel(const float* __restrict__ nr, const float* __restrict__ Wbg,
                                ushort_t* __restrict__ Tbf) {
    int n = blockIdx.x;
    int t = threadIdx.x;
    int c = t & 127, i0 = t >> 7;
    __shared__ float nrs[16];
    if (t < 16) nrs[t] = nr[n * 16 + t];
    __syncthreads();
    for (int i = i0; i < 16; i += 2) {
        float acc = 0.f;
#pragma unroll
        for (int j = 0; j < 16; ++j) acc += nrs[j] * Wbg[(i * 16 + j) * 128 + c];
        Tbf[n * 2048 + c * 16 + i] = f2bf(acc);
    }
}

// ---------------- LayerNorm over 128 -> bf16 ----------------
__global__ void ln_kernel(const float* __restrict__ x, const float* __restrict__ g,
                          const float* __restrict__ b, ushort_t* __restrict__ ef) {
    int wave = threadIdx.x >> 6, lane = threadIdx.x & 63;
    int e = blockIdx.x * 4 + wave;
    int c0 = lane, c1 = lane + 64;
    float x0 = x[e * 128 + c0], x1 = x[e * 128 + c1];
    float s = x0 + x1;
#pragma unroll
    for (int m = 1; m < 64; m <<= 1) s += __shfl_xor(s, m);
    float mean = s * (1.f / 128.f);
    float d0 = x0 - mean, d1 = x1 - mean;
    float v = d0 * d0 + d1 * d1;
#pragma unroll
    for (int m = 1; m < 64; m <<= 1) v += __shfl_xor(v, m);
    v *= (1.f / 128.f);
    float inv = rsqrtf(v + 1e-5f);
    ef[e * 128 + c0] = f2bf(d0 * inv * g[c0] + b[c0]);
    ef[e * 128 + c1] = f2bf(d1 * inv * g[c1] + b[c1]);
}

// ---------------- prep weights: WcatT(bf16, col order q|og|k|v), bcat, WdbT, WoutT ----------------
__global__ void prep_w_kernel(const float* __restrict__ Wq, const float* __restrict__ bq,
                              const float* __restrict__ Wkv, const float* __restrict__ bkv,
                              const float* __restrict__ Wog, const float* __restrict__ bog,
                              const float* __restrict__ Wdb, const float* __restrict__ Wout,
                              ushort_t* __restrict__ WcatT, float* __restrict__ bcat,
                              ushort_t* __restrict__ WdbT, ushort_t* __restrict__ WoutT) {
    int idx = blockIdx.x * 256 + threadIdx.x;  // 65536 total
    int col = idx >> 7, k = idx & 127;
    float w;
    if (col < 128) w = Wq[k * 128 + col];
    else if (col < 256) w = Wog[k * 128 + (col - 128)];
    else if (col < 384) w = Wkv[k * 256 + (col - 256)];
    else w = Wkv[k * 256 + 128 + (col - 384)];
    WcatT[idx] = f2bf(w);
    if (idx < 512) {
        float bb;
        if (idx < 128) bb = bq[idx];
        else if (idx < 256) bb = bog[idx - 128];
        else if (idx < 384) bb = bkv[idx - 256];
        else bb = bkv[idx - 384 + 128];
        bcat[idx] = bb;
    }
    if (idx < 128 * 64) {
        int c = idx >> 6, r = idx & 63;
        WdbT[idx] = f2bf(Wdb[r * 128 + c]);
    }
    if (idx < 128 * 128) {
        int c = idx >> 7, kk = idx & 127;
        WoutT[idx] = f2bf(Wout[kk * 128 + c]);
    }
}

// ---------------- MFMA GEMM: [32768,128]bf16 @ [128,512] -> qog[E,256]bf16, kv[E,256]bf16 ----------------
__global__ void __launch_bounds__(256) mfma_gemm_proj(const ushort_t* __restrict__ Abf,
                                                      const ushort_t* __restrict__ Bt,
                                                      const float* __restrict__ bias,
                                                      ushort_t* __restrict__ qog,
                                                      ushort_t* __restrict__ kvo) {
    __shared__ ushort_t As[128][136];
    __shared__ ushort_t Bs[64][136];
    int t = threadIdx.x;
    int row0 = blockIdx.y * 128;
    int n0 = blockIdx.x * 64;
#pragma unroll
    for (int u = 0; u < 8; ++u) {
        int idx = t + u * 256;
        int r = idx >> 4, seg = idx & 15;
        *(short8v*)&As[r][seg * 8] = *(const short8v*)&Abf[(size_t)(row0 + r) * 128 + seg * 8];
    }
#pragma unroll
    for (int u = 0; u < 4; ++u) {
        int idx = t + u * 256;
        int r = idx >> 4, seg = idx & 15;
        *(short8v*)&Bs[r][seg * 8] = *(const short8v*)&Bt[(size_t)(n0 + r) * 128 + seg * 8];
    }
    __syncthreads();
    int lane = t & 63, w = t >> 6;
    int wr = (w >> 1) * 64, wc = (w & 1) * 32;
    int fr = lane & 15, fk = (lane >> 4) * 8;
    f32x4 acc[4][2] = {};
#pragma unroll
    for (int kk = 0; kk < 4; ++kk) {
        short8v a[4], b[2];
#pragma unroll
        for (int m = 0; m < 4; ++m) a[m] = *(const short8v*)&As[wr + m * 16 + fr][kk * 32 + fk];
#pragma unroll
        for (int n = 0; n < 2; ++n) b[n] = *(const short8v*)&Bs[wc + n * 16 + fr][kk * 32 + fk];
#pragma unroll
        for (int m = 0; m < 4; ++m)
#pragma unroll
            for (int n = 0; n < 2; ++n)
                acc[m][n] = __builtin_amdgcn_mfma_f32_16x16x32_bf16(a[m], b[n], acc[m][n], 0, 0, 0);
    }
    __syncthreads();
    ushort_t (*stage)[72] = (ushort_t(*)[72])&As[0][0];
    int orow = (lane >> 4) * 4;
#pragma unroll
    for (int m = 0; m < 4; ++m)
#pragma unroll
        for (int n = 0; n < 2; ++n) {
            int col = wc + n * 16 + fr;
            float bv = bias[n0 + col];
#pragma unroll
            for (int j = 0; j < 4; ++j)
                stage[wr + m * 16 + orow + j][col] = f2bf(acc[m][n][j] + bv);
        }
    __syncthreads();
    ushort_t* basep; int cbase;
    if (n0 < 256) { basep = qog; cbase = n0; } else { basep = kvo; cbase = n0 - 256; }
#pragma unroll
    for (int u = 0; u < 4; ++u) {
        int idx = t + u * 256;
        int r = idx >> 3, seg = idx & 7;
        *(short8v*)&basep[(size_t)(row0 + r) * 256 + cbase + seg * 8] = *(const short8v*)&stage[r][seg * 8];
    }
}

// ---------------- MFMA GEMM: out[32768,128]f32 = updg(f32->bf16) @ WoutT + b_out ----------------
__global__ void __launch_bounds__(256) mfma_gemm_out(const float* __restrict__ Af,
                                                     const ushort_t* __restrict__ Bt,
                                                     const float* __restrict__ bias,
                                                     float* __restrict__ out) {
    __shared__ ushort_t As[128][136];
    __shared__ ushort_t Bs[64][136];
    int t = threadIdx.x;
    int row0 = blockIdx.y * 128;
    int n0 = blockIdx.x * 64;
#pragma unroll
    for (int u = 0; u < 8; ++u) {
        int idx = t + u * 256;
        int r = idx >> 4, seg = idx & 15;
        float4 f0 = *(const float4*)&Af[(size_t)(row0 + r) * 128 + seg * 8];
        float4 f1 = *(const float4*)&Af[(size_t)(row0 + r) * 128 + seg * 8 + 4];
        short8v pk;
        pk[0] = (short)f2bf(f0.x); pk[1] = (short)f2bf(f0.y);
        pk[2] = (short)f2bf(f0.z); pk[3] = (short)f2bf(f0.w);
        pk[4] = (short)f2bf(f1.x); pk[5] = (short)f2bf(f1.y);
        pk[6] = (short)f2bf(f1.z); pk[7] = (short)f2bf(f1.w);
        *(short8v*)&As[r][seg * 8] = pk;
    }
#pragma unroll
    for (int u = 0; u < 4; ++u) {
        int idx = t + u * 256;
        int r = idx >> 4, seg = idx & 15;
        *(short8v*)&Bs[r][seg * 8] = *(const short8v*)&Bt[(size_t)(n0 + r) * 128 + seg * 8];
    }
    __syncthreads();
    int lane = t & 63, w = t >> 6;
    int wr = (w >> 1) * 64, wc = (w & 1) * 32;
    int fr = lane & 15, fk = (lane >> 4) * 8;
    f32x4 acc[4][2] = {};
#pragma unroll
    for (int kk = 0; kk < 4; ++kk) {
        short8v a[4], b[2];
#pragma unroll
        for (int m = 0; m < 4; ++m) a[m] = *(const short8v*)&As[wr + m * 16 + fr][kk * 32 + fk];
#pragma unroll
        for (int n = 0; n < 2; ++n) b[n] = *(const short8v*)&Bs[wc + n * 16 + fr][kk * 32 + fk];
#pragma unroll
        for (int m = 0; m < 4; ++m)
#pragma unroll
            for (int n = 0; n < 2; ++n)
                acc[m][n] = __builtin_amdgcn_mfma_f32_16x16x32_bf16(a[m], b[n], acc[m][n], 0, 0, 0);
    }
    __syncthreads();
    float (*stage)[68] = (float(*)[68])&As[0][0];
    int orow = (lane >> 4) * 4;
#pragma unroll
    for (int m = 0; m < 4; ++m)
#pragma unroll
        for (int n = 0; n < 2; ++n) {
            int col = wc + n * 16 + fr;
            float bv = bias[n0 + col];
#pragma unroll
            for (int j = 0; j < 4; ++j)
                stage[wr + m * 16 + orow + j][col] = acc[m][n][j] + bv;
        }
    __syncthreads();
#pragma unroll
    for (int u = 0; u < 8; ++u) {
        int idx = t + u * 256;
        int r = idx >> 4, c4 = idx & 15;
        *(float4*)&out[(size_t)(row0 + r) * 128 + n0 + c4 * 4] = *(const float4*)&stage[r][c4 * 4];
    }
}

// ---------------- histogram: cnt[e1] ----------------
__global__ void hist_kernel(const int* __restrict__ eei, int* __restrict__ cnt) {
    int p = blockIdx.x * 256 + threadIdx.x;
    atomicAdd(&cnt[eei[NEE + p]], 1);
}

// ---------------- exclusive scan of cnt[32768] ----------------
__global__ void scan_kernel(const int* __restrict__ cnt, int* __restrict__ offs,
                            int* __restrict__ cursor) {
    __shared__ int part[1024];
    int t = threadIdx.x;
    int loc[32];
    int s = 0;
#pragma unroll
    for (int j = 0; j < 32; ++j) { loc[j] = cnt[t * 32 + j]; s += loc[j]; }
    part[t] = s;
    __syncthreads();
    for (int d = 1; d < 1024; d <<= 1) {
        int add = (t >= d) ? part[t - d] : 0;
        __syncthreads();
        part[t] += add;
        __syncthreads();
    }
    int excl = (t == 0) ? 0 : part[t - 1];
#pragma unroll
    for (int j = 0; j < 32; ++j) {
        offs[t * 32 + j] = excl;
        cursor[t * 32 + j] = excl;
        excl += loc[j];
    }
    if (t == 1023) offs[NE] = excl;
}

// ---------------- scatter: e0 and (n2*1024+n1) in e1-CSR rank order ----------------
__global__ void scatter_kernel(const int* __restrict__ eei, const int* __restrict__ ei,
                               int* __restrict__ cursor, int* __restrict__ e0rank,
                               int* __restrict__ n12rank) {
    int p = blockIdx.x * 256 + threadIdx.x;
    int e0 = eei[p], e1 = eei[NEE + p];
    int pos = atomicAdd(&cursor[e1], 1);
    e0rank[pos] = e0;
    n12rank[pos] = ei[e0] * 1024 + ei[e1];  // n2*1024 + n1
}

// ---------------- dense bias table: bias_tab[n2][n1][4] for ALL node pairs ----------------
// per n2-block: gate[1024,128] = NL@T[n2] (K=16), db[1024,128] = ERB@Wdb (K=64), fused
// epilogue sum_c sigmoid(gate)*db*Wtb[c,h]. B-frags loaded once per col-tile, reused
// over 2 row-groups; rows are sequential n1 (no gather anywhere).
__global__ void __launch_bounds__(256) bias_tab_kernel(
    const ushort_t* __restrict__ nl16, const ushort_t* __restrict__ Tbf,
    const ushort_t* __restrict__ WdbT, const float* __restrict__ ntr,
    const float* __restrict__ bbg, const float* __restrict__ bdb,
    const float* __restrict__ Wtb, float* __restrict__ bias_tab) {
    __shared__ ushort_t Tt[128 * 24];   // [c][16 pad 24]
    __shared__ ushort_t Wd[128 * 72];   // [c][64 pad 72]
    int t = threadIdx.x;
    int n2 = blockIdx.x;
    {
        const ushort_t* src = Tbf + (size_t)n2 * 2048;
        int c = t >> 1, hh = t & 1;
        *(int4*)&Tt[c * 24 + hh * 8] = *(const int4*)&src[c * 16 + hh * 8];
    }
#pragma unroll
    for (int u = 0; u < 4; ++u) {
        int idx = t + u * 256;
        int c = idx >> 3, seg = idx & 7;
        *(int4*)&Wd[c * 72 + seg * 8] = *(const int4*)&WdbT[c * 64 + seg * 8];
    }
    __syncthreads();
    int lane = t & 63, w = t >> 6;
    int cl = lane & 15, g = lane >> 4;
    float wtb[8][4], bdbl[8], bbgl[8];
#pragma unroll
    for (int ct = 0; ct < 8; ++ct) {
        int c = ct * 16 + cl;
        float4 wt = *(const float4*)&Wtb[c * 4];
        wtb[ct][0] = wt.x; wtb[ct][1] = wt.y; wtb[ct][2] = wt.z; wtb[ct][3] = wt.w;
        bdbl[ct] = bdb[c];
        bbgl[ct] = bbg[c];
    }
    float px2 = ntr[n2 * 3 + 0], py2 = ntr[n2 * 3 + 1], pz2 = ntr[n2 * 3 + 2];
    const float MU = 20.0f / 63.0f;
    float* outb = bias_tab + (size_t)n2 * 4096;  // [n1][4]

    for (int ch = 0; ch < 8; ++ch) {
        int rowbase = w * 256 + ch * 32;
        short8v aNL[2], ea[2], eb[2];
#pragma unroll
        for (int rg = 0; rg < 2; ++rg) {
            int row = rowbase + rg * 16 + cl;   // n1 (sequential!)
            short8v z = {0, 0, 0, 0, 0, 0, 0, 0};
            aNL[rg] = z;
            if (g < 2) aNL[rg] = *(const short8v*)&nl16[row * 16 + g * 8];
            float dx = ntr[row * 3 + 0] - px2 + 1e-8f;
            float dy = ntr[row * 3 + 1] - py2 + 1e-8f;
            float dz = ntr[row * 3 + 2] - pz2 + 1e-8f;
            float d = sqrtf(dx * dx + dy * dy + dz * dz);
#pragma unroll
            for (int j = 0; j < 8; ++j) {
                float r = (float)(g * 8 + j);
                float t0 = (d - r * MU) * 3.2f;
                float t1 = (d - (r + 32.0f) * MU) * 3.2f;
                ea[rg][j] = (short)f2bf(__expf(-t0 * t0));
                eb[rg][j] = (short)f2bf(__expf(-t1 * t1));
            }
        }
        float bacc[2][4][4] = {};
#pragma unroll
        for (int ct = 0; ct < 8; ++ct) {
            int c = ct * 16 + cl;
            short8v bT = {0, 0, 0, 0, 0, 0, 0, 0};
            if (g < 2) bT = *(const short8v*)&Tt[c * 24 + g * 8];
            short8v bW0 = *(const short8v*)&Wd[c * 72 + g * 8];
            short8v bW1 = *(const short8v*)&Wd[c * 72 + 32 + g * 8];
            float bg = bbgl[ct], bd = bdbl[ct];
            f32x4 cg = {bg, bg, bg, bg};
            f32x4 cd = {bd, bd, bd, bd};
#pragma unroll
            for (int rg = 0; rg < 2; ++rg) {
                f32x4 G = __builtin_amdgcn_mfma_f32_16x16x32_bf16(aNL[rg], bT, cg, 0, 0, 0);
                f32x4 D = __builtin_amdgcn_mfma_f32_16x16x32_bf16(ea[rg], bW0, cd, 0, 0, 0);
                D = __builtin_amdgcn_mfma_f32_16x16x32_bf16(eb[rg], bW1, D, 0, 0, 0);
#pragma unroll
                for (int j = 0; j < 4; ++j) {
                    float sg = D[j] * sigmoidf_(G[j]);
                    bacc[rg][j][0] += sg * wtb[ct][0];
                    bacc[rg][j][1] += sg * wtb[ct][1];
                    bacc[rg][j][2] += sg * wtb[ct][2];
                    bacc[rg][j][3] += sg * wtb[ct][3];
                }
            }
        }
#pragma unroll
        for (int rg = 0; rg < 2; ++rg) {
#pragma unroll
            for (int j = 0; j < 4; ++j)
#pragma unroll
                for (int h2 = 0; h2 < 4; ++h2) {
                    float v = bacc[rg][j][h2];
                    v += __shfl_xor(v, 1);
                    v += __shfl_xor(v, 2);
                    v += __shfl_xor(v, 4);
                    v += __shfl_xor(v, 8);
                    bacc[rg][j][h2] = v;
                }
            int row = rowbase + rg * 16 + g * 4 + (cl >> 2);
            outb[row * 4 + (cl & 3)] = bacc[rg][cl >> 2][cl & 3];
        }
    }
}

// ---------------- fused per-segment: qk, exp+bias, softmax-normalize, V, out-gate -> updg ----------------
// lane l owns columns c = 2l, 2l+1; head h = l>>4. 2-way unrolled; bias from dense table.
__global__ void __launch_bounds__(256) segment_kernel(const ushort_t* __restrict__ qog,
                                                      const ushort_t* __restrict__ kv,
                                                      const float* __restrict__ bias_tab,
                                                      const int* __restrict__ offs,
                                                      const int* __restrict__ e0rank,
                                                      const int* __restrict__ n12rank,
                                                      float* __restrict__ updg) {
    int t = threadIdx.x, wave = t >> 6, lane = t & 63;
    int gw = blockIdx.x * 4 + wave;
    int h = lane >> 4;
    const float scale = 0.08838834764831845f;  // 1/sqrt(128)
    for (int it = 0; it < 4; ++it) {
        int e = gw * 4 + it;
        int st = offs[e], en = offs[e + 1];
        unsigned qw = *(const unsigned*)&qog[(size_t)e * 256 + 2 * lane];
        float q0 = bf2f((ushort_t)(qw & 0xffff)), q1 = bf2f((ushort_t)(qw >> 16));
        float s = 0.f, u0 = 0.f, u1 = 0.f;
        int idx = st;
        for (; idx + 2 <= en; idx += 2) {
            int e0a = e0rank[idx], e0b = e0rank[idx + 1];
            int na = n12rank[idx], nb = n12rank[idx + 1];
            const ushort_t* kvra = kv + (size_t)e0a * 256;
            const ushort_t* kvrb = kv + (size_t)e0b * 256;
            unsigned kwa = *(const unsigned*)&kvra[2 * lane];
            unsigned vwa = *(const unsigned*)&kvra[128 + 2 * lane];
            unsigned kwb = *(const unsigned*)&kvrb[2 * lane];
            unsigned vwb = *(const unsigned*)&kvrb[128 + 2 * lane];
            float bha = bias_tab[(size_t)na * 4 + h];
            float bhb = bias_tab[(size_t)nb * 4 + h];
            float ta = q0 * bf2f((ushort_t)(kwa & 0xffff)) + q1 * bf2f((ushort_t)(kwa >> 16));
            float tb = q0 * bf2f((ushort_t)(kwb & 0xffff)) + q1 * bf2f((ushort_t)(kwb >> 16));
#pragma unroll
            for (int m = 1; m < 16; m <<= 1) { ta += __shfl_xor(ta, m); tb += __shfl_xor(tb, m); }
            float wa = __expf(ta * scale + bha);
            float wb = __expf(tb * scale + bhb);
            s += wa + wb;
            u0 += wa * bf2f((ushort_t)(vwa & 0xffff)) + wb * bf2f((ushort_t)(vwb & 0xffff));
            u1 += wa * bf2f((ushort_t)(vwa >> 16)) + wb * bf2f((ushort_t)(vwb >> 16));
        }
        if (idx < en) {
            int e0 = e0rank[idx];
            int n12 = n12rank[idx];
            const ushort_t* kvr = kv + (size_t)e0 * 256;
            unsigned kw = *(const unsigned*)&kvr[2 * lane];
            unsigned vw = *(const unsigned*)&kvr[128 + 2 * lane];
            float ta = q0 * bf2f((ushort_t)(kw & 0xffff)) + q1 * bf2f((ushort_t)(kw >> 16));
#pragma unroll
            for (int m = 1; m < 16; m <<= 1) ta += __shfl_xor(ta, m);
            float wgt = __expf(ta * scale + bias_tab[(size_t)n12 * 4 + h]);
            s += wgt;
            u0 += wgt * bf2f((ushort_t)(vw & 0xffff));
            u1 += wgt * bf2f((ushort_t)(vw >> 16));
        }
        float inv = 1.0f / (s + 1e-16f);
        unsigned ogw = *(const unsigned*)&qog[(size_t)e * 256 + 128 + 2 * lane];
        u0 = u0 * inv * sigmoidf_(bf2f((ushort_t)(ogw & 0xffff)));
        u1 = u1 * inv * sigmoidf_(bf2f((ushort_t)(ogw >> 16)));
        float2 uo; uo.x = u0; uo.y = u1;
        *(float2*)&updg[(size_t)e * 128 + 2 * lane] = uo;
    }
}

extern "C" void kernel_launch(void* const* d_in, const int* in_sizes, int n_in,
                              void* d_out, int out_size, void* d_ws, size_t ws_size,
                              hipStream_t stream) {
    const float* node_features = (const float*)d_in[0];
    const float* node_trans   = (const float*)d_in[1];
    const float* edge_features= (const float*)d_in[2];
    const int*   edge_index   = (const int*)d_in[3];
    const int*   eei          = (const int*)d_in[4];
    const float* ln_g  = (const float*)d_in[5];
    const float* ln_b  = (const float*)d_in[6];
    const float* W_nl  = (const float*)d_in[7];
    const float* b_nl  = (const float*)d_in[8];
    const float* W_nr  = (const float*)d_in[9];
    const float* b_nr  = (const float*)d_in[10];
    const float* W_bg  = (const float*)d_in[11];
    const float* b_bg  = (const float*)d_in[12];
    const float* W_db  = (const float*)d_in[13];
    const float* b_db  = (const float*)d_in[14];
    const float* W_tb  = (const float*)d_in[15];
    const float* W_q   = (const float*)d_in[16];
    const float* b_q   = (const float*)d_in[17];
    const float* W_kv  = (const float*)d_in[18];
    const float* b_kv  = (const float*)d_in[19];
    const float* W_og  = (const float*)d_in[20];
    const float* b_og  = (const float*)d_in[21];
    const float* W_out = (const float*)d_in[22];
    const float* b_out = (const float*)d_in[23];
    float* out = (float*)d_out;

    char* ws = (char*)d_ws;
    size_t off = 0;
    auto alloc = [&](size_t bytes) -> void* {
        void* p = ws + off;
        off += (bytes + 255) & ~(size_t)255;
        return p;
    };
    ushort_t* nl16  = (ushort_t*)alloc((size_t)NN * 16 * 2);
    float*    nr    = (float*)alloc((size_t)NN * 16 * 4);
    ushort_t* Tbf   = (ushort_t*)alloc((size_t)NN * 2048 * 2);
    ushort_t* WdbT  = (ushort_t*)alloc((size_t)128 * 64 * 2);
    ushort_t* WcatT = (ushort_t*)alloc((size_t)512 * 128 * 2);
    float*    bcat  = (float*)alloc((size_t)512 * 4);
    ushort_t* WoutT = (ushort_t*)alloc((size_t)128 * 128 * 2);
    ushort_t* ef_bf = (ushort_t*)alloc((size_t)NE * 128 * 2);
    ushort_t* qog   = (ushort_t*)alloc((size_t)NE * 256 * 2);
    ushort_t* kvb   = (ushort_t*)alloc((size_t)NE * 256 * 2);
    float*    bias_tab = (float*)alloc((size_t)NN * NN * 4 * 4);   // 16 MB dense table
    float*    updg  = (float*)alloc((size_t)NE * 128 * 4);
    int*      cnt   = (int*)alloc((size_t)NE * 4);
    int*      offs  = (int*)alloc((size_t)(NE + 1) * 4);
    int*      cursor  = (int*)alloc((size_t)NE * 4);
    int*      e0rank= (int*)alloc((size_t)NEE * 4);
    int*      n12rank= (int*)alloc((size_t)NEE * 4);

    hipMemsetAsync(cnt, 0, (size_t)NE * 4, stream);

    node_proj_kernel<<<NN / 4, 256, 0, stream>>>(node_features, W_nl, b_nl, W_nr, b_nr, nl16, nr);
    build_Tt_kernel<<<NN, 256, 0, stream>>>(nr, W_bg, Tbf);
    ln_kernel<<<NE / 4, 256, 0, stream>>>(edge_features, ln_g, ln_b, ef_bf);
    prep_w_kernel<<<256, 256, 0, stream>>>(W_q, b_q, W_kv, b_kv, W_og, b_og, W_db, W_out,
                                           WcatT, bcat, WdbT, WoutT);
    mfma_gemm_proj<<<dim3(8, 256), 256, 0, stream>>>(ef_bf, WcatT, bcat, qog, kvb);
    hist_kernel<<<NEE / 256, 256, 0, stream>>>(eei, cnt);
    scan_kernel<<<1, 1024, 0, stream>>>(cnt, offs, cursor);
    scatter_kernel<<<NEE / 256, 256, 0, stream>>>(eei, edge_index, cursor, e0rank, n12rank);
    bias_tab_kernel<<<NN, 256, 0, stream>>>(nl16, Tbf, WdbT, node_trans,
                                            b_bg, b_db, W_tb, bias_tab);
    segment_kernel<<<NE / 16, 256, 0, stream>>>(qog, kvb, bias_tab, offs, e0rank, n12rank, updg);
    mfma_gemm_out<<<dim3(2, 256), 256, 0, stream>>>(updg, WoutT, b_out, out);
}

// Round 10
// 443.594 us; speedup vs baseline: 1.3104x; 1.3104x over previous
//
#include <hip/hip_runtime.h>
#include <math.h>

#define NN 1024
#define NE 32768
#define NEE 262144
#define CS 384
#define CZ 128
#define CG 16
#define NH 4
#define NR 64

typedef __attribute__((ext_vector_type(8))) short short8v;
typedef __attribute__((ext_vector_type(4))) float f32x4;
typedef unsigned short ushort_t;

__device__ __forceinline__ float sigmoidf_(float x) { return 1.0f / (1.0f + __expf(-x)); }

__device__ __forceinline__ ushort_t f2bf(float x) {
    union { float f; unsigned u; } v; v.f = x;
    unsigned r = v.u + 0x7fff + ((v.u >> 16) & 1);
    return (ushort_t)(r >> 16);
}
__device__ __forceinline__ float bf2f(ushort_t x) {
    union { unsigned u; float f; } v; v.u = ((unsigned)x) << 16;
    return v.f;
}

// ---------------- node projections: nl (f32) [N,16], nr (f32) [N,16] ----------------
__global__ void node_proj_kernel(const float* __restrict__ nf,
                                 const float* __restrict__ Wl, const float* __restrict__ bl,
                                 const float* __restrict__ Wr, const float* __restrict__ br,
                                 float* __restrict__ nl, float* __restrict__ nr) {
    int wave = threadIdx.x >> 6, lane = threadIdx.x & 63;
    int n = blockIdx.x * 4 + wave;
    if (lane >= 32) return;
    bool isl = lane < 16;
    int o = isl ? lane : lane - 16;
    const float* W = isl ? Wl : Wr;
    float acc = isl ? bl[o] : br[o];
    const float* x = nf + n * CS;
    for (int k = 0; k < CS; ++k) acc += x[k] * W[k * 16 + o];
    (isl ? nl : nr)[n * 16 + o] = acc;
}

// ---------------- U[n1][c][j] (bf16) = sum_i nl[n1,i]*W_bg[(16i+j),c]  [N][128][16] ----------------
__global__ void build_U_kernel(const float* __restrict__ nl, const float* __restrict__ Wbg,
                               ushort_t* __restrict__ U) {
    int n1 = blockIdx.x;
    int t = threadIdx.x;
    __shared__ float nls[16];
    __shared__ float Uld[2048];
    if (t < 16) nls[t] = nl[n1 * 16 + t];
    __syncthreads();
    // compute: order o = j*128 + c so Wbg reads coalesce across threads
#pragma unroll
    for (int u = 0; u < 8; ++u) {
        int o = t + u * 256;
        int j = o >> 7, c = o & 127;
        float acc = 0.f;
#pragma unroll
        for (int i = 0; i < 16; ++i) acc += nls[i] * Wbg[(i * 16 + j) * 128 + c];
        Uld[c * 16 + j] = acc;
    }
    __syncthreads();
    // pack out coalesced in [c][j] layout
    short8v pk;
#pragma unroll
    for (int q = 0; q < 8; ++q) pk[q] = (short)f2bf(Uld[t * 8 + q]);
    *(short8v*)&U[(size_t)n1 * 2048 + t * 8] = pk;
}

// ---------------- LayerNorm over 128 -> bf16 ----------------
__global__ void ln_kernel(const float* __restrict__ x, const float* __restrict__ g,
                          const float* __restrict__ b, ushort_t* __restrict__ ef) {
    int wave = threadIdx.x >> 6, lane = threadIdx.x & 63;
    int e = blockIdx.x * 4 + wave;
    int c0 = lane, c1 = lane + 64;
    float x0 = x[e * 128 + c0], x1 = x[e * 128 + c1];
    float s = x0 + x1;
#pragma unroll
    for (int m = 1; m < 64; m <<= 1) s += __shfl_xor(s, m);
    float mean = s * (1.f / 128.f);
    float d0 = x0 - mean, d1 = x1 - mean;
    float v = d0 * d0 + d1 * d1;
#pragma unroll
    for (int m = 1; m < 64; m <<= 1) v += __shfl_xor(v, m);
    v *= (1.f / 128.f);
    float inv = rsqrtf(v + 1e-5f);
    ef[e * 128 + c0] = f2bf(d0 * inv * g[c0] + b[c0]);
    ef[e * 128 + c1] = f2bf(d1 * inv * g[c1] + b[c1]);
}

// ---------------- prep weights: WcatT(bf16, col order q|og|k|v), bcat, WoutT ----------------
__global__ void prep_w_kernel(const float* __restrict__ Wq, const float* __restrict__ bq,
                              const float* __restrict__ Wkv, const float* __restrict__ bkv,
                              const float* __restrict__ Wog, const float* __restrict__ bog,
                              const float* __restrict__ Wout,
                              ushort_t* __restrict__ WcatT, float* __restrict__ bcat,
                              ushort_t* __restrict__ WoutT) {
    int idx = blockIdx.x * 256 + threadIdx.x;  // 65536 total
    int col = idx >> 7, k = idx & 127;
    float w;
    if (col < 128) w = Wq[k * 128 + col];
    else if (col < 256) w = Wog[k * 128 + (col - 128)];
    else if (col < 384) w = Wkv[k * 256 + (col - 256)];
    else w = Wkv[k * 256 + 128 + (col - 384)];
    WcatT[idx] = f2bf(w);
    if (idx < 512) {
        float bb;
        if (idx < 128) bb = bq[idx];
        else if (idx < 256) bb = bog[idx - 128];
        else if (idx < 384) bb = bkv[idx - 256];
        else bb = bkv[idx - 384 + 128];
        bcat[idx] = bb;
    }
    if (idx < 128 * 128) {
        int c = idx >> 7, kk = idx & 127;
        WoutT[idx] = f2bf(Wout[kk * 128 + c]);
    }
}

// ---------------- MFMA GEMM: [32768,128]bf16 @ [128,512] -> qog[E,256]bf16, kv[E,256]bf16 ----------------
__global__ void __launch_bounds__(256) mfma_gemm_proj(const ushort_t* __restrict__ Abf,
                                                      const ushort_t* __restrict__ Bt,
                                                      const float* __restrict__ bias,
                                                      ushort_t* __restrict__ qog,
                                                      ushort_t* __restrict__ kvo) {
    __shared__ ushort_t As[128][136];
    __shared__ ushort_t Bs[64][136];
    int t = threadIdx.x;
    int row0 = blockIdx.y * 128;
    int n0 = blockIdx.x * 64;
#pragma unroll
    for (int u = 0; u < 8; ++u) {
        int idx = t + u * 256;
        int r = idx >> 4, seg = idx & 15;
        *(short8v*)&As[r][seg * 8] = *(const short8v*)&Abf[(size_t)(row0 + r) * 128 + seg * 8];
    }
#pragma unroll
    for (int u = 0; u < 4; ++u) {
        int idx = t + u * 256;
        int r = idx >> 4, seg = idx & 15;
        *(short8v*)&Bs[r][seg * 8] = *(const short8v*)&Bt[(size_t)(n0 + r) * 128 + seg * 8];
    }
    __syncthreads();
    int lane = t & 63, w = t >> 6;
    int wr = (w >> 1) * 64, wc = (w & 1) * 32;
    int fr = lane & 15, fk = (lane >> 4) * 8;
    f32x4 acc[4][2] = {};
#pragma unroll
    for (int kk = 0; kk < 4; ++kk) {
        short8v a[4], b[2];
#pragma unroll
        for (int m = 0; m < 4; ++m) a[m] = *(const short8v*)&As[wr + m * 16 + fr][kk * 32 + fk];
#pragma unroll
        for (int n = 0; n < 2; ++n) b[n] = *(const short8v*)&Bs[wc + n * 16 + fr][kk * 32 + fk];
#pragma unroll
        for (int m = 0; m < 4; ++m)
#pragma unroll
            for (int n = 0; n < 2; ++n)
                acc[m][n] = __builtin_amdgcn_mfma_f32_16x16x32_bf16(a[m], b[n], acc[m][n], 0, 0, 0);
    }
    __syncthreads();
    ushort_t (*stage)[72] = (ushort_t(*)[72])&As[0][0];
    int orow = (lane >> 4) * 4;
#pragma unroll
    for (int m = 0; m < 4; ++m)
#pragma unroll
        for (int n = 0; n < 2; ++n) {
            int col = wc + n * 16 + fr;
            float bv = bias[n0 + col];
#pragma unroll
            for (int j = 0; j < 4; ++j)
                stage[wr + m * 16 + orow + j][col] = f2bf(acc[m][n][j] + bv);
        }
    __syncthreads();
    ushort_t* basep; int cbase;
    if (n0 < 256) { basep = qog; cbase = n0; } else { basep = kvo; cbase = n0 - 256; }
#pragma unroll
    for (int u = 0; u < 4; ++u) {
        int idx = t + u * 256;
        int r = idx >> 3, seg = idx & 7;
        *(short8v*)&basep[(size_t)(row0 + r) * 256 + cbase + seg * 8] = *(const short8v*)&stage[r][seg * 8];
    }
}

// ---------------- MFMA GEMM: out[32768,128]f32 = updg(f32->bf16) @ WoutT + b_out ----------------
__global__ void __launch_bounds__(256) mfma_gemm_out(const float* __restrict__ Af,
                                                     const ushort_t* __restrict__ Bt,
                                                     const float* __restrict__ bias,
                                                     float* __restrict__ out) {
    __shared__ ushort_t As[128][136];
    __shared__ ushort_t Bs[64][136];
    int t = threadIdx.x;
    int row0 = blockIdx.y * 128;
    int n0 = blockIdx.x * 64;
#pragma unroll
    for (int u = 0; u < 8; ++u) {
        int idx = t + u * 256;
        int r = idx >> 4, seg = idx & 15;
        float4 f0 = *(const float4*)&Af[(size_t)(row0 + r) * 128 + seg * 8];
        float4 f1 = *(const float4*)&Af[(size_t)(row0 + r) * 128 + seg * 8 + 4];
        short8v pk;
        pk[0] = (short)f2bf(f0.x); pk[1] = (short)f2bf(f0.y);
        pk[2] = (short)f2bf(f0.z); pk[3] = (short)f2bf(f0.w);
        pk[4] = (short)f2bf(f1.x); pk[5] = (short)f2bf(f1.y);
        pk[6] = (short)f2bf(f1.z); pk[7] = (short)f2bf(f1.w);
        *(short8v*)&As[r][seg * 8] = pk;
    }
#pragma unroll
    for (int u = 0; u < 4; ++u) {
        int idx = t + u * 256;
        int r = idx >> 4, seg = idx & 15;
        *(short8v*)&Bs[r][seg * 8] = *(const short8v*)&Bt[(size_t)(n0 + r) * 128 + seg * 8];
    }
    __syncthreads();
    int lane = t & 63, w = t >> 6;
    int wr = (w >> 1) * 64, wc = (w & 1) * 32;
    int fr = lane & 15, fk = (lane >> 4) * 8;
    f32x4 acc[4][2] = {};
#pragma unroll
    for (int kk = 0; kk < 4; ++kk) {
        short8v a[4], b[2];
#pragma unroll
        for (int m = 0; m < 4; ++m) a[m] = *(const short8v*)&As[wr + m * 16 + fr][kk * 32 + fk];
#pragma unroll
        for (int n = 0; n < 2; ++n) b[n] = *(const short8v*)&Bs[wc + n * 16 + fr][kk * 32 + fk];
#pragma unroll
        for (int m = 0; m < 4; ++m)
#pragma unroll
            for (int n = 0; n < 2; ++n)
                acc[m][n] = __builtin_amdgcn_mfma_f32_16x16x32_bf16(a[m], b[n], acc[m][n], 0, 0, 0);
    }
    __syncthreads();
    float (*stage)[68] = (float(*)[68])&As[0][0];
    int orow = (lane >> 4) * 4;
#pragma unroll
    for (int m = 0; m < 4; ++m)
#pragma unroll
        for (int n = 0; n < 2; ++n) {
            int col = wc + n * 16 + fr;
            float bv = bias[n0 + col];
#pragma unroll
            for (int j = 0; j < 4; ++j)
                stage[wr + m * 16 + orow + j][col] = acc[m][n][j] + bv;
        }
    __syncthreads();
#pragma unroll
    for (int u = 0; u < 8; ++u) {
        int idx = t + u * 256;
        int r = idx >> 4, c4 = idx & 15;
        *(float4*)&out[(size_t)(row0 + r) * 128 + n0 + c4 * 4] = *(const float4*)&stage[r][c4 * 4];
    }
}

// ---------------- histogram: cnt[e1] ----------------
__global__ void hist_kernel(const int* __restrict__ eei, int* __restrict__ cnt) {
    int p = blockIdx.x * 256 + threadIdx.x;
    atomicAdd(&cnt[eei[NEE + p]], 1);
}

// ---------------- exclusive scan of cnt[32768] ----------------
__global__ void scan_kernel(const int* __restrict__ cnt, int* __restrict__ offs,
                            int* __restrict__ cursor) {
    __shared__ int part[1024];
    int t = threadIdx.x;
    int loc[32];
    int s = 0;
#pragma unroll
    for (int j = 0; j < 32; ++j) { loc[j] = cnt[t * 32 + j]; s += loc[j]; }
    part[t] = s;
    __syncthreads();
    for (int d = 1; d < 1024; d <<= 1) {
        int add = (t >= d) ? part[t - d] : 0;
        __syncthreads();
        part[t] += add;
        __syncthreads();
    }
    int excl = (t == 0) ? 0 : part[t - 1];
#pragma unroll
    for (int j = 0; j < 32; ++j) {
        offs[t * 32 + j] = excl;
        cursor[t * 32 + j] = excl;
        excl += loc[j];
    }
    if (t == 1023) offs[NE] = excl;
}

// ---------------- scatter: e0 and n2 in e1-CSR rank order ----------------
__global__ void scatter_kernel(const int* __restrict__ eei, const int* __restrict__ ei,
                               int* __restrict__ cursor, int* __restrict__ e0rank,
                               int* __restrict__ n2rank) {
    int p = blockIdx.x * 256 + threadIdx.x;
    int e0 = eei[p], e1 = eei[NEE + p];
    int pos = atomicAdd(&cursor[e1], 1);
    e0rank[pos] = e0;
    n2rank[pos] = ei[e0];
}

// ---------------- fused segment: bias (gate+rbf) + qk + softmax + V + out-gate -> updg ----------------
// Per segment: n1 = ei[e] fixed -> U[n1] row loop-invariant (64B/lane).
// lane l owns c0=2l, c1=2l+1; head h = l>>4.
__global__ void __launch_bounds__(256) segment_kernel(const ushort_t* __restrict__ qog,
                                                      const ushort_t* __restrict__ kv,
                                                      const ushort_t* __restrict__ U,
                                                      const float* __restrict__ nrm,
                                                      const float* __restrict__ ntr,
                                                      const float* __restrict__ Wdb,
                                                      const float* __restrict__ bbg,
                                                      const float* __restrict__ bdb,
                                                      const float* __restrict__ Wtb,
                                                      const int* __restrict__ ei,
                                                      const int* __restrict__ offs,
                                                      const int* __restrict__ e0rank,
                                                      const int* __restrict__ n2rank,
                                                      float* __restrict__ updg) {
    __shared__ float Wds[NR * 128];  // 32 KB, [r][c]
    int t = threadIdx.x, wave = t >> 6, lane = t & 63;
#pragma unroll
    for (int u = 0; u < 8; ++u) ((float4*)Wds)[t + u * 256] = ((const float4*)Wdb)[t + u * 256];
    __syncthreads();

    int c0 = 2 * lane, c1 = 2 * lane + 1;
    int h = lane >> 4;
    // lane-constant epilogue params
    float bbg0 = bbg[c0], bbg1 = bbg[c1];
    float bdb0 = bdb[c0], bdb1 = bdb[c1];
    float4 wt0 = *(const float4*)&Wtb[c0 * 4];
    float4 wt1 = *(const float4*)&Wtb[c1 * 4];

    int gw = blockIdx.x * 4 + wave;
    const float scale = 0.08838834764831845f;  // 1/sqrt(128)
    const float MU = 20.0f / 63.0f;
    const float INVMU = 63.0f / 20.0f;

    for (int it = 0; it < 4; ++it) {
        int e = gw * 4 + it;
        int st = offs[e], en = offs[e + 1];
        int n1 = ei[e];
        float px1 = ntr[n1 * 3 + 0], py1 = ntr[n1 * 3 + 1], pz1 = ntr[n1 * 3 + 2];
        // U[n1] fragment: 32 bf16 = this lane's two columns, [c][j] layout
        const ushort_t* Urow = U + (size_t)n1 * 2048 + lane * 32;
        short8v u0 = *(const short8v*)&Urow[0];   // c0, j0..7
        short8v u1 = *(const short8v*)&Urow[8];   // c0, j8..15
        short8v u2 = *(const short8v*)&Urow[16];  // c1, j0..7
        short8v u3 = *(const short8v*)&Urow[24];  // c1, j8..15
        unsigned qw = *(const unsigned*)&qog[(size_t)e * 256 + c0];
        float q0 = bf2f((ushort_t)(qw & 0xffff)), q1 = bf2f((ushort_t)(qw >> 16));
        float s = 0.f, uo0 = 0.f, uo1 = 0.f;
        for (int idx = st; idx < en; ++idx) {
            int e0 = e0rank[idx];
            int n2 = n2rank[idx];
            const ushort_t* kvr = kv + (size_t)e0 * 256;
            unsigned kw = *(const unsigned*)&kvr[c0];
            unsigned vw = *(const unsigned*)&kvr[128 + c0];
            // ---- gate: sum_j nr[n2,j] * U[n1,c,j] ----
            float4 nr0 = *(const float4*)&nrm[n2 * 16 + 0];
            float4 nr1 = *(const float4*)&nrm[n2 * 16 + 4];
            float4 nr2 = *(const float4*)&nrm[n2 * 16 + 8];
            float4 nr3 = *(const float4*)&nrm[n2 * 16 + 12];
            float nrv[16] = {nr0.x, nr0.y, nr0.z, nr0.w, nr1.x, nr1.y, nr1.z, nr1.w,
                             nr2.x, nr2.y, nr2.z, nr2.w, nr3.x, nr3.y, nr3.z, nr3.w};
            float g0 = bbg0, g1 = bbg1;
#pragma unroll
            for (int j = 0; j < 8; ++j) {
                g0 += nrv[j] * bf2f((ushort_t)u0[j]);
                g1 += nrv[j] * bf2f((ushort_t)u2[j]);
            }
#pragma unroll
            for (int j = 0; j < 8; ++j) {
                g0 += nrv[8 + j] * bf2f((ushort_t)u1[j]);
                g1 += nrv[8 + j] * bf2f((ushort_t)u3[j]);
            }
            // ---- distance + windowed RBF @ Wdb ----
            float dx = px1 - ntr[n2 * 3 + 0] + 1e-8f;
            float dy = py1 - ntr[n2 * 3 + 1] + 1e-8f;
            float dz = pz1 - ntr[n2 * 3 + 2] + 1e-8f;
            float d = sqrtf(dx * dx + dy * dy + dz * dz);
            int r0i = (int)(d * INVMU) - 7;
            r0i = (r0i < 0) ? 0 : ((r0i > 48) ? 48 : r0i);
            float db0 = bdb0, db1 = bdb1;
#pragma unroll
            for (int wnd = 0; wnd < 16; ++wnd) {
                int r = r0i + wnd;
                float tt = (d - (float)r * MU) * 3.2f;
                float erb = __expf(-tt * tt);
                float2 wv = *(const float2*)&Wds[r * 128 + c0];
                db0 += erb * wv.x;
                db1 += erb * wv.y;
            }
            // ---- bias heads ----
            float s0 = db0 * sigmoidf_(g0), s1 = db1 * sigmoidf_(g1);
            float bh0 = s0 * wt0.x + s1 * wt1.x;
            float bh1 = s0 * wt0.y + s1 * wt1.y;
            float bh2 = s0 * wt0.z + s1 * wt1.z;
            float bh3 = s0 * wt0.w + s1 * wt1.w;
#pragma unroll
            for (int m = 1; m < 64; m <<= 1) {
                bh0 += __shfl_xor(bh0, m); bh1 += __shfl_xor(bh1, m);
                bh2 += __shfl_xor(bh2, m); bh3 += __shfl_xor(bh3, m);
            }
            float bh = (h == 0) ? bh0 : (h == 1) ? bh1 : (h == 2) ? bh2 : bh3;
            // ---- qk (per-head over 16 lanes = 32 dims) ----
            float ta = q0 * bf2f((ushort_t)(kw & 0xffff)) + q1 * bf2f((ushort_t)(kw >> 16));
#pragma unroll
            for (int m = 1; m < 16; m <<= 1) ta += __shfl_xor(ta, m);
            float wgt = __expf(ta * scale + bh);
            s += wgt;
            uo0 += wgt * bf2f((ushort_t)(vw & 0xffff));
            uo1 += wgt * bf2f((ushort_t)(vw >> 16));
        }
        float inv = 1.0f / (s + 1e-16f);
        unsigned ogw = *(const unsigned*)&qog[(size_t)e * 256 + 128 + c0];
        uo0 = uo0 * inv * sigmoidf_(bf2f((ushort_t)(ogw & 0xffff)));
        uo1 = uo1 * inv * sigmoidf_(bf2f((ushort_t)(ogw >> 16)));
        float2 uo; uo.x = uo0; uo.y = uo1;
        *(float2*)&updg[(size_t)e * 128 + c0] = uo;
    }
}

extern "C" void kernel_launch(void* const* d_in, const int* in_sizes, int n_in,
                              void* d_out, int out_size, void* d_ws, size_t ws_size,
                              hipStream_t stream) {
    const float* node_features = (const float*)d_in[0];
    const float* node_trans   = (const float*)d_in[1];
    const float* edge_features= (const float*)d_in[2];
    const int*   edge_index   = (const int*)d_in[3];
    const int*   eei          = (const int*)d_in[4];
    const float* ln_g  = (const float*)d_in[5];
    const float* ln_b  = (const float*)d_in[6];
    const float* W_nl  = (const float*)d_in[7];
    const float* b_nl  = (const float*)d_in[8];
    const float* W_nr  = (const float*)d_in[9];
    const float* b_nr  = (const float*)d_in[10];
    const float* W_bg  = (const float*)d_in[11];
    const float* b_bg  = (const float*)d_in[12];
    const float* W_db  = (const float*)d_in[13];
    const float* b_db  = (const float*)d_in[14];
    const float* W_tb  = (const float*)d_in[15];
    const float* W_q   = (const float*)d_in[16];
    const float* b_q   = (const float*)d_in[17];
    const float* W_kv  = (const float*)d_in[18];
    const float* b_kv  = (const float*)d_in[19];
    const float* W_og  = (const float*)d_in[20];
    const float* b_og  = (const float*)d_in[21];
    const float* W_out = (const float*)d_in[22];
    const float* b_out = (const float*)d_in[23];
    float* out = (float*)d_out;

    char* ws = (char*)d_ws;
    size_t off = 0;
    auto alloc = [&](size_t bytes) -> void* {
        void* p = ws + off;
        off += (bytes + 255) & ~(size_t)255;
        return p;
    };
    float*    nl    = (float*)alloc((size_t)NN * 16 * 4);
    float*    nrm   = (float*)alloc((size_t)NN * 16 * 4);
    ushort_t* U     = (ushort_t*)alloc((size_t)NN * 2048 * 2);
    ushort_t* WcatT = (ushort_t*)alloc((size_t)512 * 128 * 2);
    float*    bcat  = (float*)alloc((size_t)512 * 4);
    ushort_t* WoutT = (ushort_t*)alloc((size_t)128 * 128 * 2);
    ushort_t* ef_bf = (ushort_t*)alloc((size_t)NE * 128 * 2);
    ushort_t* qog   = (ushort_t*)alloc((size_t)NE * 256 * 2);
    ushort_t* kvb   = (ushort_t*)alloc((size_t)NE * 256 * 2);
    float*    updg  = (float*)alloc((size_t)NE * 128 * 4);
    int*      cnt   = (int*)alloc((size_t)NE * 4);
    int*      offs  = (int*)alloc((size_t)(NE + 1) * 4);
    int*      cursor= (int*)alloc((size_t)NE * 4);
    int*      e0rank= (int*)alloc((size_t)NEE * 4);
    int*      n2rank= (int*)alloc((size_t)NEE * 4);

    hipMemsetAsync(cnt, 0, (size_t)NE * 4, stream);

    node_proj_kernel<<<NN / 4, 256, 0, stream>>>(node_features, W_nl, b_nl, W_nr, b_nr, nl, nrm);
    build_U_kernel<<<NN, 256, 0, stream>>>(nl, W_bg, U);
    ln_kernel<<<NE / 4, 256, 0, stream>>>(edge_features, ln_g, ln_b, ef_bf);
    prep_w_kernel<<<256, 256, 0, stream>>>(W_q, b_q, W_kv, b_kv, W_og, b_og, W_out,
                                           WcatT, bcat, WoutT);
    mfma_gemm_proj<<<dim3(8, 256), 256, 0, stream>>>(ef_bf, WcatT, bcat, qog, kvb);
    hist_kernel<<<NEE / 256, 256, 0, stream>>>(eei, cnt);
    scan_kernel<<<1, 1024, 0, stream>>>(cnt, offs, cursor);
    scatter_kernel<<<NEE / 256, 256, 0, stream>>>(eei, edge_index, cursor, e0rank, n2rank);
    segment_kernel<<<NE / 16, 256, 0, stream>>>(qog, kvb, U, nrm, node_trans, W_db,
                                                b_bg, b_db, W_tb, edge_index,
                                                offs, e0rank, n2rank, updg);
    mfma_gemm_out<<<dim3(2, 256), 256, 0, stream>>>(updg, WoutT, b_out, out);
}

// Round 11
// 440.515 us; speedup vs baseline: 1.3195x; 1.0070x over previous
//
#include <hip/hip_runtime.h>
#include <math.h>

#define NN 1024
#define NE 32768
#define NEE 262144
#define CS 384
#define CZ 128
#define CG 16
#define NH 4
#define NR 64

typedef __attribute__((ext_vector_type(8))) short short8v;
typedef __attribute__((ext_vector_type(4))) float f32x4;
typedef unsigned short ushort_t;

__device__ __forceinline__ float sigmoidf_(float x) { return 1.0f / (1.0f + __expf(-x)); }

__device__ __forceinline__ ushort_t f2bf(float x) {
    union { float f; unsigned u; } v; v.f = x;
    unsigned r = v.u + 0x7fff + ((v.u >> 16) & 1);
    return (ushort_t)(r >> 16);
}
__device__ __forceinline__ float bf2f(ushort_t x) {
    union { unsigned u; float f; } v; v.u = ((unsigned)x) << 16;
    return v.f;
}

// ---------------- node projections: nl (f32) [N,16], nr (f32) [N,16] ----------------
__global__ void node_proj_kernel(const float* __restrict__ nf,
                                 const float* __restrict__ Wl, const float* __restrict__ bl,
                                 const float* __restrict__ Wr, const float* __restrict__ br,
                                 float* __restrict__ nl, float* __restrict__ nr) {
    int wave = threadIdx.x >> 6, lane = threadIdx.x & 63;
    int n = blockIdx.x * 4 + wave;
    if (lane >= 32) return;
    bool isl = lane < 16;
    int o = isl ? lane : lane - 16;
    const float* W = isl ? Wl : Wr;
    float acc = isl ? bl[o] : br[o];
    const float* x = nf + n * CS;
    for (int k = 0; k < CS; ++k) acc += x[k] * W[k * 16 + o];
    (isl ? nl : nr)[n * 16 + o] = acc;
}

// ---------------- U[n1][c][j] (bf16) = sum_i nl[n1,i]*W_bg[(16i+j),c]  [N][128][16] ----------------
__global__ void build_U_kernel(const float* __restrict__ nl, const float* __restrict__ Wbg,
                               ushort_t* __restrict__ U) {
    int n1 = blockIdx.x;
    int t = threadIdx.x;
    __shared__ float nls[16];
    __shared__ float Uld[2048];
    if (t < 16) nls[t] = nl[n1 * 16 + t];
    __syncthreads();
#pragma unroll
    for (int u = 0; u < 8; ++u) {
        int o = t + u * 256;
        int j = o >> 7, c = o & 127;
        float acc = 0.f;
#pragma unroll
        for (int i = 0; i < 16; ++i) acc += nls[i] * Wbg[(i * 16 + j) * 128 + c];
        Uld[c * 16 + j] = acc;
    }
    __syncthreads();
    short8v pk;
#pragma unroll
    for (int q = 0; q < 8; ++q) pk[q] = (short)f2bf(Uld[t * 8 + q]);
    *(short8v*)&U[(size_t)n1 * 2048 + t * 8] = pk;
}

// ---------------- LayerNorm over 128 -> bf16 ----------------
__global__ void ln_kernel(const float* __restrict__ x, const float* __restrict__ g,
                          const float* __restrict__ b, ushort_t* __restrict__ ef) {
    int wave = threadIdx.x >> 6, lane = threadIdx.x & 63;
    int e = blockIdx.x * 4 + wave;
    int c0 = lane, c1 = lane + 64;
    float x0 = x[e * 128 + c0], x1 = x[e * 128 + c1];
    float s = x0 + x1;
#pragma unroll
    for (int m = 1; m < 64; m <<= 1) s += __shfl_xor(s, m);
    float mean = s * (1.f / 128.f);
    float d0 = x0 - mean, d1 = x1 - mean;
    float v = d0 * d0 + d1 * d1;
#pragma unroll
    for (int m = 1; m < 64; m <<= 1) v += __shfl_xor(v, m);
    v *= (1.f / 128.f);
    float inv = rsqrtf(v + 1e-5f);
    ef[e * 128 + c0] = f2bf(d0 * inv * g[c0] + b[c0]);
    ef[e * 128 + c1] = f2bf(d1 * inv * g[c1] + b[c1]);
}

// ---------------- prep weights: WcatT(bf16, col order q|og|k|v), bcat, WoutT ----------------
__global__ void prep_w_kernel(const float* __restrict__ Wq, const float* __restrict__ bq,
                              const float* __restrict__ Wkv, const float* __restrict__ bkv,
                              const float* __restrict__ Wog, const float* __restrict__ bog,
                              const float* __restrict__ Wout,
                              ushort_t* __restrict__ WcatT, float* __restrict__ bcat,
                              ushort_t* __restrict__ WoutT) {
    int idx = blockIdx.x * 256 + threadIdx.x;  // 65536 total
    int col = idx >> 7, k = idx & 127;
    float w;
    if (col < 128) w = Wq[k * 128 + col];
    else if (col < 256) w = Wog[k * 128 + (col - 128)];
    else if (col < 384) w = Wkv[k * 256 + (col - 256)];
    else w = Wkv[k * 256 + 128 + (col - 384)];
    WcatT[idx] = f2bf(w);
    if (idx < 512) {
        float bb;
        if (idx < 128) bb = bq[idx];
        else if (idx < 256) bb = bog[idx - 128];
        else if (idx < 384) bb = bkv[idx - 256];
        else bb = bkv[idx - 384 + 128];
        bcat[idx] = bb;
    }
    if (idx < 128 * 128) {
        int c = idx >> 7, kk = idx & 127;
        WoutT[idx] = f2bf(Wout[kk * 128 + c]);
    }
}

// ---------------- MFMA GEMM: [32768,128]bf16 @ [128,512] -> qog[E,256]bf16, kv[E,256]bf16 ----------------
__global__ void __launch_bounds__(256) mfma_gemm_proj(const ushort_t* __restrict__ Abf,
                                                      const ushort_t* __restrict__ Bt,
                                                      const float* __restrict__ bias,
                                                      ushort_t* __restrict__ qog,
                                                      ushort_t* __restrict__ kvo) {
    __shared__ ushort_t As[128][136];
    __shared__ ushort_t Bs[64][136];
    int t = threadIdx.x;
    int row0 = blockIdx.y * 128;
    int n0 = blockIdx.x * 64;
#pragma unroll
    for (int u = 0; u < 8; ++u) {
        int idx = t + u * 256;
        int r = idx >> 4, seg = idx & 15;
        *(short8v*)&As[r][seg * 8] = *(const short8v*)&Abf[(size_t)(row0 + r) * 128 + seg * 8];
    }
#pragma unroll
    for (int u = 0; u < 4; ++u) {
        int idx = t + u * 256;
        int r = idx >> 4, seg = idx & 15;
        *(short8v*)&Bs[r][seg * 8] = *(const short8v*)&Bt[(size_t)(n0 + r) * 128 + seg * 8];
    }
    __syncthreads();
    int lane = t & 63, w = t >> 6;
    int wr = (w >> 1) * 64, wc = (w & 1) * 32;
    int fr = lane & 15, fk = (lane >> 4) * 8;
    f32x4 acc[4][2] = {};
#pragma unroll
    for (int kk = 0; kk < 4; ++kk) {
        short8v a[4], b[2];
#pragma unroll
        for (int m = 0; m < 4; ++m) a[m] = *(const short8v*)&As[wr + m * 16 + fr][kk * 32 + fk];
#pragma unroll
        for (int n = 0; n < 2; ++n) b[n] = *(const short8v*)&Bs[wc + n * 16 + fr][kk * 32 + fk];
#pragma unroll
        for (int m = 0; m < 4; ++m)
#pragma unroll
            for (int n = 0; n < 2; ++n)
                acc[m][n] = __builtin_amdgcn_mfma_f32_16x16x32_bf16(a[m], b[n], acc[m][n], 0, 0, 0);
    }
    __syncthreads();
    ushort_t (*stage)[72] = (ushort_t(*)[72])&As[0][0];
    int orow = (lane >> 4) * 4;
#pragma unroll
    for (int m = 0; m < 4; ++m)
#pragma unroll
        for (int n = 0; n < 2; ++n) {
            int col = wc + n * 16 + fr;
            float bv = bias[n0 + col];
#pragma unroll
            for (int j = 0; j < 4; ++j)
                stage[wr + m * 16 + orow + j][col] = f2bf(acc[m][n][j] + bv);
        }
    __syncthreads();
    ushort_t* basep; int cbase;
    if (n0 < 256) { basep = qog; cbase = n0; } else { basep = kvo; cbase = n0 - 256; }
#pragma unroll
    for (int u = 0; u < 4; ++u) {
        int idx = t + u * 256;
        int r = idx >> 3, seg = idx & 7;
        *(short8v*)&basep[(size_t)(row0 + r) * 256 + cbase + seg * 8] = *(const short8v*)&stage[r][seg * 8];
    }
}

// ---------------- MFMA GEMM: out[32768,128]f32 = updg(f32->bf16) @ WoutT + b_out ----------------
__global__ void __launch_bounds__(256) mfma_gemm_out(const float* __restrict__ Af,
                                                     const ushort_t* __restrict__ Bt,
                                                     const float* __restrict__ bias,
                                                     float* __restrict__ out) {
    __shared__ ushort_t As[128][136];
    __shared__ ushort_t Bs[64][136];
    int t = threadIdx.x;
    int row0 = blockIdx.y * 128;
    int n0 = blockIdx.x * 64;
#pragma unroll
    for (int u = 0; u < 8; ++u) {
        int idx = t + u * 256;
        int r = idx >> 4, seg = idx & 15;
        float4 f0 = *(const float4*)&Af[(size_t)(row0 + r) * 128 + seg * 8];
        float4 f1 = *(const float4*)&Af[(size_t)(row0 + r) * 128 + seg * 8 + 4];
        short8v pk;
        pk[0] = (short)f2bf(f0.x); pk[1] = (short)f2bf(f0.y);
        pk[2] = (short)f2bf(f0.z); pk[3] = (short)f2bf(f0.w);
        pk[4] = (short)f2bf(f1.x); pk[5] = (short)f2bf(f1.y);
        pk[6] = (short)f2bf(f1.z); pk[7] = (short)f2bf(f1.w);
        *(short8v*)&As[r][seg * 8] = pk;
    }
#pragma unroll
    for (int u = 0; u < 4; ++u) {
        int idx = t + u * 256;
        int r = idx >> 4, seg = idx & 15;
        *(short8v*)&Bs[r][seg * 8] = *(const short8v*)&Bt[(size_t)(n0 + r) * 128 + seg * 8];
    }
    __syncthreads();
    int lane = t & 63, w = t >> 6;
    int wr = (w >> 1) * 64, wc = (w & 1) * 32;
    int fr = lane & 15, fk = (lane >> 4) * 8;
    f32x4 acc[4][2] = {};
#pragma unroll
    for (int kk = 0; kk < 4; ++kk) {
        short8v a[4], b[2];
#pragma unroll
        for (int m = 0; m < 4; ++m) a[m] = *(const short8v*)&As[wr + m * 16 + fr][kk * 32 + fk];
#pragma unroll
        for (int n = 0; n < 2; ++n) b[n] = *(const short8v*)&Bs[wc + n * 16 + fr][kk * 32 + fk];
#pragma unroll
        for (int m = 0; m < 4; ++m)
#pragma unroll
            for (int n = 0; n < 2; ++n)
                acc[m][n] = __builtin_amdgcn_mfma_f32_16x16x32_bf16(a[m], b[n], acc[m][n], 0, 0, 0);
    }
    __syncthreads();
    float (*stage)[68] = (float(*)[68])&As[0][0];
    int orow = (lane >> 4) * 4;
#pragma unroll
    for (int m = 0; m < 4; ++m)
#pragma unroll
        for (int n = 0; n < 2; ++n) {
            int col = wc + n * 16 + fr;
            float bv = bias[n0 + col];
#pragma unroll
            for (int j = 0; j < 4; ++j)
                stage[wr + m * 16 + orow + j][col] = acc[m][n][j] + bv;
        }
    __syncthreads();
#pragma unroll
    for (int u = 0; u < 8; ++u) {
        int idx = t + u * 256;
        int r = idx >> 4, c4 = idx & 15;
        *(float4*)&out[(size_t)(row0 + r) * 128 + n0 + c4 * 4] = *(const float4*)&stage[r][c4 * 4];
    }
}

// ---------------- histogram: cnt[e1] ----------------
__global__ void hist_kernel(const int* __restrict__ eei, int* __restrict__ cnt) {
    int p = blockIdx.x * 256 + threadIdx.x;
    atomicAdd(&cnt[eei[NEE + p]], 1);
}

// ---------------- exclusive scan of cnt[32768] ----------------
__global__ void scan_kernel(const int* __restrict__ cnt, int* __restrict__ offs,
                            int* __restrict__ cursor) {
    __shared__ int part[1024];
    int t = threadIdx.x;
    int loc[32];
    int s = 0;
#pragma unroll
    for (int j = 0; j < 32; ++j) { loc[j] = cnt[t * 32 + j]; s += loc[j]; }
    part[t] = s;
    __syncthreads();
    for (int d = 1; d < 1024; d <<= 1) {
        int add = (t >= d) ? part[t - d] : 0;
        __syncthreads();
        part[t] += add;
        __syncthreads();
    }
    int excl = (t == 0) ? 0 : part[t - 1];
#pragma unroll
    for (int j = 0; j < 32; ++j) {
        offs[t * 32 + j] = excl;
        cursor[t * 32 + j] = excl;
        excl += loc[j];
    }
    if (t == 1023) offs[NE] = excl;
}

// ---------------- scatter: e0 and n2 in e1-CSR rank order ----------------
__global__ void scatter_kernel(const int* __restrict__ eei, const int* __restrict__ ei,
                               int* __restrict__ cursor, int* __restrict__ e0rank,
                               int* __restrict__ n2rank) {
    int p = blockIdx.x * 256 + threadIdx.x;
    int e0 = eei[p], e1 = eei[NEE + p];
    int pos = atomicAdd(&cursor[e1], 1);
    e0rank[pos] = e0;
    n2rank[pos] = ei[e0];
}

// ---------------- fused segment: bias (gate + dedup'd RBF) + qk + softmax + V + out-gate ----------------
// Per segment: n1 = ei[e] fixed -> U[n1] row loop-invariant. lane l owns c0=2l, c1=2l+1; head h=l>>4.
// RBF: lane (l&15) computes the one exp for its window tap; taps broadcast via __shfl.
__global__ void __launch_bounds__(256) segment_kernel(const ushort_t* __restrict__ qog,
                                                      const ushort_t* __restrict__ kv,
                                                      const ushort_t* __restrict__ U,
                                                      const float* __restrict__ nrm,
                                                      const float* __restrict__ ntr,
                                                      const float* __restrict__ Wdb,
                                                      const float* __restrict__ bbg,
                                                      const float* __restrict__ bdb,
                                                      const float* __restrict__ Wtb,
                                                      const int* __restrict__ ei,
                                                      const int* __restrict__ offs,
                                                      const int* __restrict__ e0rank,
                                                      const int* __restrict__ n2rank,
                                                      float* __restrict__ updg) {
    __shared__ float Wds[NR * 128];  // 32 KB, [r][c]
    int t = threadIdx.x, wave = t >> 6, lane = t & 63;
#pragma unroll
    for (int u = 0; u < 8; ++u) ((float4*)Wds)[t + u * 256] = ((const float4*)Wdb)[t + u * 256];
    __syncthreads();

    int c0 = 2 * lane, c1 = 2 * lane + 1;
    int h = lane >> 4;
    int lq = lane & 15;
    float bbg0 = bbg[c0], bbg1 = bbg[c1];
    float bdb0 = bdb[c0], bdb1 = bdb[c1];
    float4 wt0 = *(const float4*)&Wtb[c0 * 4];
    float4 wt1 = *(const float4*)&Wtb[c1 * 4];

    int gw = blockIdx.x * 4 + wave;
    const float scale = 0.08838834764831845f;  // 1/sqrt(128)
    const float MU = 20.0f / 63.0f;
    const float INVMU = 63.0f / 20.0f;

    for (int it = 0; it < 4; ++it) {
        int e = gw * 4 + it;
        int st = offs[e], en = offs[e + 1];
        int n1 = ei[e];
        float px1 = ntr[n1 * 3 + 0], py1 = ntr[n1 * 3 + 1], pz1 = ntr[n1 * 3 + 2];
        const ushort_t* Urow = U + (size_t)n1 * 2048 + lane * 32;
        short8v u0 = *(const short8v*)&Urow[0];   // c0, j0..7
        short8v u1 = *(const short8v*)&Urow[8];   // c0, j8..15
        short8v u2 = *(const short8v*)&Urow[16];  // c1, j0..7
        short8v u3 = *(const short8v*)&Urow[24];  // c1, j8..15
        unsigned qw = *(const unsigned*)&qog[(size_t)e * 256 + c0];
        float q0 = bf2f((ushort_t)(qw & 0xffff)), q1 = bf2f((ushort_t)(qw >> 16));
        float s = 0.f, uo0 = 0.f, uo1 = 0.f;
        int idx = st;
        for (; idx + 2 <= en; idx += 2) {
            int e0a = e0rank[idx], e0b = e0rank[idx + 1];
            int n2a = n2rank[idx], n2b = n2rank[idx + 1];
            const ushort_t* kvra = kv + (size_t)e0a * 256;
            const ushort_t* kvrb = kv + (size_t)e0b * 256;
            unsigned kwa = *(const unsigned*)&kvra[c0];
            unsigned vwa = *(const unsigned*)&kvra[128 + c0];
            unsigned kwb = *(const unsigned*)&kvrb[c0];
            unsigned vwb = *(const unsigned*)&kvrb[128 + c0];
            float4 naA = *(const float4*)&nrm[n2a * 16 + 0];
            float4 nbA = *(const float4*)&nrm[n2a * 16 + 4];
            float4 ncA = *(const float4*)&nrm[n2a * 16 + 8];
            float4 ndA = *(const float4*)&nrm[n2a * 16 + 12];
            float4 naB = *(const float4*)&nrm[n2b * 16 + 0];
            float4 nbB = *(const float4*)&nrm[n2b * 16 + 4];
            float4 ncB = *(const float4*)&nrm[n2b * 16 + 8];
            float4 ndB = *(const float4*)&nrm[n2b * 16 + 12];
            // gate A
            float g0a = bbg0, g1a = bbg1, g0b = bbg0, g1b = bbg1;
            g0a += naA.x * bf2f((ushort_t)u0[0]) + naA.y * bf2f((ushort_t)u0[1]) +
                   naA.z * bf2f((ushort_t)u0[2]) + naA.w * bf2f((ushort_t)u0[3]) +
                   nbA.x * bf2f((ushort_t)u0[4]) + nbA.y * bf2f((ushort_t)u0[5]) +
                   nbA.z * bf2f((ushort_t)u0[6]) + nbA.w * bf2f((ushort_t)u0[7]) +
                   ncA.x * bf2f((ushort_t)u1[0]) + ncA.y * bf2f((ushort_t)u1[1]) +
                   ncA.z * bf2f((ushort_t)u1[2]) + ncA.w * bf2f((ushort_t)u1[3]) +
                   ndA.x * bf2f((ushort_t)u1[4]) + ndA.y * bf2f((ushort_t)u1[5]) +
                   ndA.z * bf2f((ushort_t)u1[6]) + ndA.w * bf2f((ushort_t)u1[7]);
            g1a += naA.x * bf2f((ushort_t)u2[0]) + naA.y * bf2f((ushort_t)u2[1]) +
                   naA.z * bf2f((ushort_t)u2[2]) + naA.w * bf2f((ushort_t)u2[3]) +
                   nbA.x * bf2f((ushort_t)u2[4]) + nbA.y * bf2f((ushort_t)u2[5]) +
                   nbA.z * bf2f((ushort_t)u2[6]) + nbA.w * bf2f((ushort_t)u2[7]) +
                   ncA.x * bf2f((ushort_t)u3[0]) + ncA.y * bf2f((ushort_t)u3[1]) +
                   ncA.z * bf2f((ushort_t)u3[2]) + ncA.w * bf2f((ushort_t)u3[3]) +
                   ndA.x * bf2f((ushort_t)u3[4]) + ndA.y * bf2f((ushort_t)u3[5]) +
                   ndA.z * bf2f((ushort_t)u3[6]) + ndA.w * bf2f((ushort_t)u3[7]);
            // gate B
            g0b += naB.x * bf2f((ushort_t)u0[0]) + naB.y * bf2f((ushort_t)u0[1]) +
                   naB.z * bf2f((ushort_t)u0[2]) + naB.w * bf2f((ushort_t)u0[3]) +
                   nbB.x * bf2f((ushort_t)u0[4]) + nbB.y * bf2f((ushort_t)u0[5]) +
                   nbB.z * bf2f((ushort_t)u0[6]) + nbB.w * bf2f((ushort_t)u0[7]) +
                   ncB.x * bf2f((ushort_t)u1[0]) + ncB.y * bf2f((ushort_t)u1[1]) +
                   ncB.z * bf2f((ushort_t)u1[2]) + ncB.w * bf2f((ushort_t)u1[3]) +
                   ndB.x * bf2f((ushort_t)u1[4]) + ndB.y * bf2f((ushort_t)u1[5]) +
                   ndB.z * bf2f((ushort_t)u1[6]) + ndB.w * bf2f((ushort_t)u1[7]);
            g1b += naB.x * bf2f((ushort_t)u2[0]) + naB.y * bf2f((ushort_t)u2[1]) +
                   naB.z * bf2f((ushort_t)u2[2]) + naB.w * bf2f((ushort_t)u2[3]) +
                   nbB.x * bf2f((ushort_t)u2[4]) + nbB.y * bf2f((ushort_t)u2[5]) +
                   nbB.z * bf2f((ushort_t)u2[6]) + nbB.w * bf2f((ushort_t)u2[7]) +
                   ncB.x * bf2f((ushort_t)u3[0]) + ncB.y * bf2f((ushort_t)u3[1]) +
                   ncB.z * bf2f((ushort_t)u3[2]) + ncB.w * bf2f((ushort_t)u3[3]) +
                   ndB.x * bf2f((ushort_t)u3[4]) + ndB.y * bf2f((ushort_t)u3[5]) +
                   ndB.z * bf2f((ushort_t)u3[6]) + ndB.w * bf2f((ushort_t)u3[7]);
            // distance + window base
            float dxa = px1 - ntr[n2a * 3 + 0] + 1e-8f;
            float dya = py1 - ntr[n2a * 3 + 1] + 1e-8f;
            float dza = pz1 - ntr[n2a * 3 + 2] + 1e-8f;
            float da = sqrtf(dxa * dxa + dya * dya + dza * dza);
            float dxb = px1 - ntr[n2b * 3 + 0] + 1e-8f;
            float dyb = py1 - ntr[n2b * 3 + 1] + 1e-8f;
            float dzb = pz1 - ntr[n2b * 3 + 2] + 1e-8f;
            float db_ = sqrtf(dxb * dxb + dyb * dyb + dzb * dzb);
            int r0a = (int)(da * INVMU) - 7; r0a = (r0a < 0) ? 0 : ((r0a > 48) ? 48 : r0a);
            int r0b = (int)(db_ * INVMU) - 7; r0b = (r0b < 0) ? 0 : ((r0b > 48) ? 48 : r0b);
            // one exp per pair (lane lq owns tap lq)
            float tta = (da - (float)(r0a + lq) * MU) * 3.2f;
            float erba = __expf(-tta * tta);
            float ttb = (db_ - (float)(r0b + lq) * MU) * 3.2f;
            float erbb = __expf(-ttb * ttb);
            float db0a = bdb0, db1a = bdb1, db0b = bdb0, db1b = bdb1;
#pragma unroll
            for (int wnd = 0; wnd < 16; ++wnd) {
                float era = __shfl(erba, wnd);
                float erb2 = __shfl(erbb, wnd);
                float2 wva = *(const float2*)&Wds[(r0a + wnd) * 128 + c0];
                float2 wvb = *(const float2*)&Wds[(r0b + wnd) * 128 + c0];
                db0a += era * wva.x; db1a += era * wva.y;
                db0b += erb2 * wvb.x; db1b += erb2 * wvb.y;
            }
            // bias heads
            float s0a = db0a * sigmoidf_(g0a), s1a = db1a * sigmoidf_(g1a);
            float s0b = db0b * sigmoidf_(g0b), s1b = db1b * sigmoidf_(g1b);
            float bh0a = s0a * wt0.x + s1a * wt1.x, bh1a = s0a * wt0.y + s1a * wt1.y;
            float bh2a = s0a * wt0.z + s1a * wt1.z, bh3a = s0a * wt0.w + s1a * wt1.w;
            float bh0b = s0b * wt0.x + s1b * wt1.x, bh1b = s0b * wt0.y + s1b * wt1.y;
            float bh2b = s0b * wt0.z + s1b * wt1.z, bh3b = s0b * wt0.w + s1b * wt1.w;
#pragma unroll
            for (int m = 1; m < 64; m <<= 1) {
                bh0a += __shfl_xor(bh0a, m); bh1a += __shfl_xor(bh1a, m);
                bh2a += __shfl_xor(bh2a, m); bh3a += __shfl_xor(bh3a, m);
                bh0b += __shfl_xor(bh0b, m); bh1b += __shfl_xor(bh1b, m);
                bh2b += __shfl_xor(bh2b, m); bh3b += __shfl_xor(bh3b, m);
            }
            float bha = (h == 0) ? bh0a : (h == 1) ? bh1a : (h == 2) ? bh2a : bh3a;
            float bhb = (h == 0) ? bh0b : (h == 1) ? bh1b : (h == 2) ? bh2b : bh3b;
            // qk
            float taa = q0 * bf2f((ushort_t)(kwa & 0xffff)) + q1 * bf2f((ushort_t)(kwa >> 16));
            float tab = q0 * bf2f((ushort_t)(kwb & 0xffff)) + q1 * bf2f((ushort_t)(kwb >> 16));
#pragma unroll
            for (int m = 1; m < 16; m <<= 1) { taa += __shfl_xor(taa, m); tab += __shfl_xor(tab, m); }
            float wa = __expf(taa * scale + bha);
            float wb = __expf(tab * scale + bhb);
            s += wa + wb;
            uo0 += wa * bf2f((ushort_t)(vwa & 0xffff)) + wb * bf2f((ushort_t)(vwb & 0xffff));
            uo1 += wa * bf2f((ushort_t)(vwa >> 16)) + wb * bf2f((ushort_t)(vwb >> 16));
        }
        if (idx < en) {
            int e0 = e0rank[idx];
            int n2 = n2rank[idx];
            const ushort_t* kvr = kv + (size_t)e0 * 256;
            unsigned kw = *(const unsigned*)&kvr[c0];
            unsigned vw = *(const unsigned*)&kvr[128 + c0];
            float4 na = *(const float4*)&nrm[n2 * 16 + 0];
            float4 nb = *(const float4*)&nrm[n2 * 16 + 4];
            float4 nc = *(const float4*)&nrm[n2 * 16 + 8];
            float4 nd = *(const float4*)&nrm[n2 * 16 + 12];
            float g0 = bbg0, g1 = bbg1;
            g0 += na.x * bf2f((ushort_t)u0[0]) + na.y * bf2f((ushort_t)u0[1]) +
                  na.z * bf2f((ushort_t)u0[2]) + na.w * bf2f((ushort_t)u0[3]) +
                  nb.x * bf2f((ushort_t)u0[4]) + nb.y * bf2f((ushort_t)u0[5]) +
                  nb.z * bf2f((ushort_t)u0[6]) + nb.w * bf2f((ushort_t)u0[7]) +
                  nc.x * bf2f((ushort_t)u1[0]) + nc.y * bf2f((ushort_t)u1[1]) +
                  nc.z * bf2f((ushort_t)u1[2]) + nc.w * bf2f((ushort_t)u1[3]) +
                  nd.x * bf2f((ushort_t)u1[4]) + nd.y * bf2f((ushort_t)u1[5]) +
                  nd.z * bf2f((ushort_t)u1[6]) + nd.w * bf2f((ushort_t)u1[7]);
            g1 += na.x * bf2f((ushort_t)u2[0]) + na.y * bf2f((ushort_t)u2[1]) +
                  na.z * bf2f((ushort_t)u2[2]) + na.w * bf2f((ushort_t)u2[3]) +
                  nb.x * bf2f((ushort_t)u2[4]) + nb.y * bf2f((ushort_t)u2[5]) +
                  nb.z * bf2f((ushort_t)u2[6]) + nb.w * bf2f((ushort_t)u2[7]) +
                  nc.x * bf2f((ushort_t)u3[0]) + nc.y * bf2f((ushort_t)u3[1]) +
                  nc.z * bf2f((ushort_t)u3[2]) + nc.w * bf2f((ushort_t)u3[3]) +
                  nd.x * bf2f((ushort_t)u3[4]) + nd.y * bf2f((ushort_t)u3[5]) +
                  nd.z * bf2f((ushort_t)u3[6]) + nd.w * bf2f((ushort_t)u3[7]);
            float dx = px1 - ntr[n2 * 3 + 0] + 1e-8f;
            float dy = py1 - ntr[n2 * 3 + 1] + 1e-8f;
            float dz = pz1 - ntr[n2 * 3 + 2] + 1e-8f;
            float d = sqrtf(dx * dx + dy * dy + dz * dz);
            int r0i = (int)(d * INVMU) - 7;
            r0i = (r0i < 0) ? 0 : ((r0i > 48) ? 48 : r0i);
            float tt = (d - (float)(r0i + lq) * MU) * 3.2f;
            float erb = __expf(-tt * tt);
            float db0 = bdb0, db1 = bdb1;
#pragma unroll
            for (int wnd = 0; wnd < 16; ++wnd) {
                float er = __shfl(erb, wnd);
                float2 wv = *(const float2*)&Wds[(r0i + wnd) * 128 + c0];
                db0 += er * wv.x;
                db1 += er * wv.y;
            }
            float s0 = db0 * sigmoidf_(g0), s1 = db1 * sigmoidf_(g1);
            float bh0 = s0 * wt0.x + s1 * wt1.x;
            float bh1 = s0 * wt0.y + s1 * wt1.y;
            float bh2 = s0 * wt0.z + s1 * wt1.z;
            float bh3 = s0 * wt0.w + s1 * wt1.w;
#pragma unroll
            for (int m = 1; m < 64; m <<= 1) {
                bh0 += __shfl_xor(bh0, m); bh1 += __shfl_xor(bh1, m);
                bh2 += __shfl_xor(bh2, m); bh3 += __shfl_xor(bh3, m);
            }
            float bh = (h == 0) ? bh0 : (h == 1) ? bh1 : (h == 2) ? bh2 : bh3;
            float ta = q0 * bf2f((ushort_t)(kw & 0xffff)) + q1 * bf2f((ushort_t)(kw >> 16));
#pragma unroll
            for (int m = 1; m < 16; m <<= 1) ta += __shfl_xor(ta, m);
            float wgt = __expf(ta * scale + bh);
            s += wgt;
            uo0 += wgt * bf2f((ushort_t)(vw & 0xffff));
            uo1 += wgt * bf2f((ushort_t)(vw >> 16));
        }
        float inv = 1.0f / (s + 1e-16f);
        unsigned ogw = *(const unsigned*)&qog[(size_t)e * 256 + 128 + c0];
        uo0 = uo0 * inv * sigmoidf_(bf2f((ushort_t)(ogw & 0xffff)));
        uo1 = uo1 * inv * sigmoidf_(bf2f((ushort_t)(ogw >> 16)));
        float2 uo; uo.x = uo0; uo.y = uo1;
        *(float2*)&updg[(size_t)e * 128 + c0] = uo;
    }
}

extern "C" void kernel_launch(void* const* d_in, const int* in_sizes, int n_in,
                              void* d_out, int out_size, void* d_ws, size_t ws_size,
                              hipStream_t stream) {
    const float* node_features = (const float*)d_in[0];
    const float* node_trans   = (const float*)d_in[1];
    const float* edge_features= (const float*)d_in[2];
    const int*   edge_index   = (const int*)d_in[3];
    const int*   eei          = (const int*)d_in[4];
    const float* ln_g  = (const float*)d_in[5];
    const float* ln_b  = (const float*)d_in[6];
    const float* W_nl  = (const float*)d_in[7];
    const float* b_nl  = (const float*)d_in[8];
    const float* W_nr  = (const float*)d_in[9];
    const float* b_nr  = (const float*)d_in[10];
    const float* W_bg  = (const float*)d_in[11];
    const float* b_bg  = (const float*)d_in[12];
    const float* W_db  = (const float*)d_in[13];
    const float* b_db  = (const float*)d_in[14];
    const float* W_tb  = (const float*)d_in[15];
    const float* W_q   = (const float*)d_in[16];
    const float* b_q   = (const float*)d_in[17];
    const float* W_kv  = (const float*)d_in[18];
    const float* b_kv  = (const float*)d_in[19];
    const float* W_og  = (const float*)d_in[20];
    const float* b_og  = (const float*)d_in[21];
    const float* W_out = (const float*)d_in[22];
    const float* b_out = (const float*)d_in[23];
    float* out = (float*)d_out;

    char* ws = (char*)d_ws;
    size_t off = 0;
    auto alloc = [&](size_t bytes) -> void* {
        void* p = ws + off;
        off += (bytes + 255) & ~(size_t)255;
        return p;
    };
    float*    nl    = (float*)alloc((size_t)NN * 16 * 4);
    float*    nrm   = (float*)alloc((size_t)NN * 16 * 4);
    ushort_t* U     = (ushort_t*)alloc((size_t)NN * 2048 * 2);
    ushort_t* WcatT = (ushort_t*)alloc((size_t)512 * 128 * 2);
    float*    bcat  = (float*)alloc((size_t)512 * 4);
    ushort_t* WoutT = (ushort_t*)alloc((size_t)128 * 128 * 2);
    ushort_t* ef_bf = (ushort_t*)alloc((size_t)NE * 128 * 2);
    ushort_t* qog   = (ushort_t*)alloc((size_t)NE * 256 * 2);
    ushort_t* kvb   = (ushort_t*)alloc((size_t)NE * 256 * 2);
    float*    updg  = (float*)alloc((size_t)NE * 128 * 4);
    int*      cnt   = (int*)alloc((size_t)NE * 4);
    int*      offs  = (int*)alloc((size_t)(NE + 1) * 4);
    int*      cursor= (int*)alloc((size_t)NE * 4);
    int*      e0rank= (int*)alloc((size_t)NEE * 4);
    int*      n2rank= (int*)alloc((size_t)NEE * 4);

    hipMemsetAsync(cnt, 0, (size_t)NE * 4, stream);

    node_proj_kernel<<<NN / 4, 256, 0, stream>>>(node_features, W_nl, b_nl, W_nr, b_nr, nl, nrm);
    build_U_kernel<<<NN, 256, 0, stream>>>(nl, W_bg, U);
    ln_kernel<<<NE / 4, 256, 0, stream>>>(edge_features, ln_g, ln_b, ef_bf);
    prep_w_kernel<<<256, 256, 0, stream>>>(W_q, b_q, W_kv, b_kv, W_og, b_og, W_out,
                                           WcatT, bcat, WoutT);
    mfma_gemm_proj<<<dim3(8, 256), 256, 0, stream>>>(ef_bf, WcatT, bcat, qog, kvb);
    hist_kernel<<<NEE / 256, 256, 0, stream>>>(eei, cnt);
    scan_kernel<<<1, 1024, 0, stream>>>(cnt, offs, cursor);
    scatter_kernel<<<NEE / 256, 256, 0, stream>>>(eei, edge_index, cursor, e0rank, n2rank);
    segment_kernel<<<NE / 16, 256, 0, stream>>>(qog, kvb, U, nrm, node_trans, W_db,
                                                b_bg, b_db, W_tb, edge_index,
                                                offs, e0rank, n2rank, updg);
    mfma_gemm_out<<<dim3(2, 256), 256, 0, stream>>>(updg, WoutT, b_out, out);
}